// Round 1
// baseline (883.973 us; speedup 1.0000x reference)
//
#include <hip/hip_runtime.h>
#include <stdint.h>

typedef __bf16 bf16x8 __attribute__((ext_vector_type(8)));
typedef float f32x4v __attribute__((ext_vector_type(4)));

typedef __attribute__((address_space(1))) const void gconst_t;
typedef __attribute__((address_space(3))) void lds_t;

// global -> LDS direct copy, 16 B per lane. LDS dest = wave-uniform base + lane*16.
#define GLL16(gp, sp) __builtin_amdgcn_global_load_lds((gconst_t*)(uintptr_t)(gp), (lds_t*)(uintptr_t)(sp), 16, 0, 0)

__device__ __forceinline__ unsigned short f2bf(float f) {
  unsigned int u = __float_as_uint(f);
  u = (u + 0x7FFFu + ((u >> 16) & 1u)) >> 16;
  return (unsigned short)u;
}
__device__ __forceinline__ float bf2f(unsigned int b) {
  return __uint_as_float(b << 16);
}

// ---------------- sizes ----------------
// x: (64,512,32,32) f32. padded NHWC: [n][34][34][512] bf16
#define SPP 1156                    // 34*34
#define A_ELEMS (64u * SPP * 512u)  // 37,879,808

// ---------------- bn param prep ----------------
__global__ __launch_bounds__(512) void bnprep(
    const float* __restrict__ g1, const float* __restrict__ b1,
    const float* __restrict__ m1, const float* __restrict__ v1,
    const float* __restrict__ g2, const float* __restrict__ b2,
    const float* __restrict__ m2, const float* __restrict__ v2,
    float* __restrict__ bnp) {
  int t = threadIdx.x;
  float i1 = g1[t] * rsqrtf(v1[t] + 1e-5f);
  bnp[t] = i1;
  bnp[512 + t] = b1[t] - m1[t] * i1;
  float i2 = g2[t] * rsqrtf(v2[t] + 1e-5f);
  bnp[1024 + t] = i2;
  bnp[1536 + t] = b2[t] - m2[t] * i2;
}

// ---------------- weight transform: w[co][ci][dy][dx] f32 -> wt[tap][co][ci] bf16 ----------------
__global__ __launch_bounds__(256) void wtrans(const float* __restrict__ w1, const float* __restrict__ w2,
                                              unsigned short* __restrict__ w1t, unsigned short* __restrict__ w2t) {
  unsigned e = blockIdx.x * 256u + threadIdx.x;
  if (e >= 4718592u) return;
  const float* w = (e < 2359296u) ? w1 : w2;
  unsigned short* o = (e < 2359296u) ? w1t : w2t;
  unsigned r = (e < 2359296u) ? e : (e - 2359296u);
  unsigned ci = r & 511u, co = (r >> 9) & 511u, tt = r >> 18;
  o[r] = f2bf(w[(co * 512u + ci) * 9u + tt]);
}

// ---------------- bn1+relu, write padded NHWC bf16, per-(n,ci,yblk) partial sums ----------------
__global__ __launch_bounds__(256) void bn1_relu_stage(const float* __restrict__ x, const float* __restrict__ bnp,
                                                      unsigned short* __restrict__ Ap, float* __restrict__ partial) {
  int bid = blockIdx.x;
  int n = bid >> 6, ciblk = (bid >> 3) & 7, yblk = bid & 7;
  int ci0 = ciblk * 64, y0 = yblk * 4;
  int t = threadIdx.x;
  __shared__ __align__(16) float vals[64 * 128];
  __shared__ float ivs[64], bbs[64];
  if (t < 64) { ivs[t] = bnp[ci0 + t]; bbs[t] = bnp[512 + ci0 + t]; }
  __syncthreads();
#pragma unroll
  for (int i = 0; i < 8; ++i) {
    int f4 = i * 256 + t;
    int cil = f4 >> 5, xq = f4 & 31;
    const float* src = x + ((size_t)(n * 512 + ci0 + cil)) * 1024 + y0 * 32 + xq * 4;
    f32x4v v = *(const f32x4v*)src;
    float iv = ivs[cil], bb = bbs[cil];
    f32x4v r;
    r[0] = fmaxf(fmaf(v[0], iv, bb), 0.f);
    r[1] = fmaxf(fmaf(v[1], iv, bb), 0.f);
    r[2] = fmaxf(fmaf(v[2], iv, bb), 0.f);
    r[3] = fmaxf(fmaf(v[3], iv, bb), 0.f);
    *(f32x4v*)&vals[cil * 128 + xq * 4] = r;
  }
  __syncthreads();
  // partial sums per ci (deterministic)
  {
    int cil = t >> 2, q = t & 3;
    float s = 0.f;
#pragma unroll
    for (int j = 0; j < 32; ++j) s += vals[cil * 128 + q * 32 + j];
    s += __shfl_xor(s, 1);
    s += __shfl_xor(s, 2);
    if (q == 0) partial[((size_t)n * 512 + ci0 + cil) * 8 + yblk] = s;
  }
  // transpose to padded NHWC bf16
  {
    int yx = t >> 1, half = t & 1;
    int y = y0 + (yx >> 5), xx = yx & 31;
    unsigned short* dp = Ap + ((size_t)((n * 34 + y + 1) * 34 + (xx + 1))) * 512 + ci0 + half * 32;
    unsigned wrd[16];
#pragma unroll
    for (int j = 0; j < 16; ++j) {
      unsigned lo = f2bf(vals[(half * 32 + 2 * j) * 128 + yx]);
      unsigned hi = f2bf(vals[(half * 32 + 2 * j + 1) * 128 + yx]);
      wrd[j] = lo | (hi << 16);
    }
#pragma unroll
    for (int k = 0; k < 4; ++k) {
      uint4 u;
      u.x = wrd[k * 4]; u.y = wrd[k * 4 + 1]; u.z = wrd[k * 4 + 2]; u.w = wrd[k * 4 + 3];
      *(uint4*)(dp + k * 8) = u;
    }
  }
}

// ---------------- probe + analytic mask; writes pred_probe ----------------
__global__ __launch_bounds__(256) void probe_mask(const float* __restrict__ partial,
                                                  const float* __restrict__ fc1w, const float* __restrict__ fc1b,
                                                  const float* __restrict__ fc2w, const float* __restrict__ fc2b,
                                                  float* __restrict__ maskp, float* __restrict__ probeout) {
  int n = blockIdx.x, t = threadIdx.x;
  int lane = t & 63, wv = t >> 6;
  __shared__ float gl[512], sl[512], zl[240], hl[240], dzl[240], logl[10], red[4];
  __shared__ int idx2[2];
  for (int c = t; c < 512; c += 256) {
    const float* pp = partial + ((size_t)n * 512 + c) * 8;
    float s = 0.f;
#pragma unroll
    for (int j = 0; j < 8; ++j) s += pp[j];
    gl[c] = s * (1.f / 1024.f);
  }
  __syncthreads();
  if (t < 240) {
    float z = fc1b[t];
    const float* wr = fc1w + t * 512;
    for (int c = 0; c < 512; ++c) z = fmaf(gl[c], wr[c], z);
    zl[t] = z;
    float u = 5.f * z;
    float sp = (u > 20.f) ? u : log1pf(expf(u));
    hl[t] = sp * 0.2f;
  }
  __syncthreads();
  if (t < 10) {
    float L = fc2b[t];
    const float* wr = fc2w + t * 240;
    for (int h = 0; h < 240; ++h) L = fmaf(hl[h], wr[h], L);
    logl[t] = L;
    probeout[n * 10 + t] = L;
  }
  __syncthreads();
  if (t == 0) {
    float b1v = -1e30f, b2v = -1e30f; int i1 = 0, i2 = 0;
    for (int j = 0; j < 10; ++j) {
      float v = logl[j];
      if (v > b1v) { b2v = b1v; i2 = i1; b1v = v; i1 = j; }
      else if (v > b2v) { b2v = v; i2 = j; }
    }
    idx2[0] = i1; idx2[1] = i2;
  }
  __syncthreads();
  if (t < 240) {
    float dh = fc2w[idx2[0] * 240 + t] + fc2w[idx2[1] * 240 + t];
    float u = 5.f * zl[t];
    float sg = 1.f / (1.f + expf(-u));
    dzl[t] = dh * sg;
  }
  __syncthreads();
  for (int c = t; c < 512; c += 256) {
    float s = 0.f;
    for (int h = 0; h < 240; ++h) s = fmaf(dzl[h], fc1w[h * 512 + c], s);
    sl[c] = s;
  }
  __syncthreads();
  float m = fmaxf(sl[t], sl[t + 256]);
#pragma unroll
  for (int o = 32; o > 0; o >>= 1) m = fmaxf(m, __shfl_xor(m, o));
  if (lane == 0) red[wv] = m;
  __syncthreads();
  float mx = fmaxf(fmaxf(red[0], red[1]), fmaxf(red[2], red[3]));
  float e0 = expf(sl[t] - mx), e1 = expf(sl[t + 256] - mx);
  float sum = e0 + e1;
#pragma unroll
  for (int o = 32; o > 0; o >>= 1) sum += __shfl_xor(sum, o);
  __syncthreads();
  if (lane == 0) red[wv] = sum;
  __syncthreads();
  float inv = 2.f / (red[0] + red[1] + red[2] + red[3]);
  maskp[(size_t)n * 512 + t] = e0 * inv;
  maskp[(size_t)n * 512 + t + 256] = e1 * inv;
}

// ---------------- in-place mask multiply on padded NHWC bf16 ----------------
__global__ __launch_bounds__(256) void apply_mask(unsigned short* __restrict__ Ap, const float* __restrict__ maskp) {
  int n = blockIdx.y;
  size_t off = (size_t)n * (SPP * 512) + (size_t)blockIdx.x * 2048 + threadIdx.x * 8;
  int ci0 = (int)(threadIdx.x * 8) & 511;
  uint4 v = *(uint4*)(Ap + off);
  const float* mp = maskp + n * 512 + ci0;
  unsigned r0, r1;
  r0 = f2bf(bf2f(v.x & 0xFFFFu) * mp[0]); r1 = f2bf(bf2f(v.x >> 16) * mp[1]); v.x = r0 | (r1 << 16);
  r0 = f2bf(bf2f(v.y & 0xFFFFu) * mp[2]); r1 = f2bf(bf2f(v.y >> 16) * mp[3]); v.y = r0 | (r1 << 16);
  r0 = f2bf(bf2f(v.z & 0xFFFFu) * mp[4]); r1 = f2bf(bf2f(v.z >> 16) * mp[5]); v.z = r0 | (r1 << 16);
  r0 = f2bf(bf2f(v.w & 0xFFFFu) * mp[6]); r1 = f2bf(bf2f(v.w >> 16) * mp[7]); v.w = r0 | (r1 << 16);
  *(uint4*)(Ap + off) = v;
}

// ---------------- implicit-GEMM conv (9 taps x K=512), 128x128 tile, BK=64 ----------------
// MODE 1: epilogue bn2+relu -> bf16 padded NHWC (Hout)
// MODE 2: epilogue += x residual -> f32 NCHW (outp), via LDS transpose
template <int MODE>
__global__ __launch_bounds__(256, 2) void conv_gemm(
    const unsigned short* __restrict__ Ain,
    const unsigned short* __restrict__ Wt,
    const float* __restrict__ bnp,
    unsigned short* __restrict__ Hout,
    const float* __restrict__ xres,
    float* __restrict__ outp) {
  __shared__ __align__(16) float smem[64 * 132];  // 33792 B: staging (32 KiB) / MODE2 epilogue
  short* sA = (short*)smem;
  short* sB = sA + 8192;

  const int t = threadIdx.x;
  const int lane = t & 63;
  const int wv = t >> 6;
  const int wm = wv >> 1, wn = wv & 1;
  const int bx = blockIdx.x;
  const int tn = bx & 3, tm = bx >> 2;
  const int n = tm >> 3;
  const int y0 = (tm & 7) * 4;
  const int co0 = tn * 128;

  int arow[4], acol[4], brow[4];
  short* sdstA[4];
  short* sdstB[4];
#pragma unroll
  for (int i = 0; i < 4; ++i) {
    int li = i * 256 + t;
    int r = li >> 3, c = li & 7;
    arow[i] = (y0 + (r >> 5)) * 34 + (r & 31);  // padded row, before +dy/+dx
    acol[i] = c * 8;
    brow[i] = (co0 + r) * 512 + c * 8;
    sdstA[i] = sA + (i * 256 + wv * 64) * 8;
    sdstB[i] = sB + (i * 256 + wv * 64) * 8;
  }
  const unsigned short* An = Ain + (size_t)n * (SPP * 512);

  f32x4v acc[4][4];
  const f32x4v zero = {0.f, 0.f, 0.f, 0.f};
#pragma unroll
  for (int mi = 0; mi < 4; ++mi)
#pragma unroll
    for (int ni = 0; ni < 4; ++ni) acc[mi][ni] = zero;

  const int aoffb = (wm * 64 + (lane & 15)) * 64 + (lane >> 4) * 8;
  const int boffb = (wn * 64 + (lane & 15)) * 64 + (lane >> 4) * 8;

  for (int tap = 0; tap < 9; ++tap) {
    const int dy = (tap * 11) >> 5;   // tap/3
    const int dx = tap - dy * 3;
    const unsigned short* Atap = An + (size_t)(dy * 34 + dx) * 512;
    const unsigned short* Btap = Wt + (size_t)tap * (512 * 512);
    for (int k8 = 0; k8 < 8; ++k8) {
      const int kin = k8 * 64;
#pragma unroll
      for (int i = 0; i < 4; ++i) {
        GLL16(Atap + (size_t)arow[i] * 512 + (kin + acol[i]), sdstA[i]);
        GLL16(Btap + (brow[i] + kin), sdstB[i]);
      }
      __syncthreads();  // drains vmcnt: tiles complete
      bf16x8 af[4][2], bfr[4][2];
#pragma unroll
      for (int mi = 0; mi < 4; ++mi) {
        af[mi][0] = *(const bf16x8*)(sA + aoffb + mi * 1024);
        af[mi][1] = *(const bf16x8*)(sA + aoffb + mi * 1024 + 32);
      }
#pragma unroll
      for (int ni = 0; ni < 4; ++ni) {
        bfr[ni][0] = *(const bf16x8*)(sB + boffb + ni * 1024);
        bfr[ni][1] = *(const bf16x8*)(sB + boffb + ni * 1024 + 32);
      }
#pragma unroll
      for (int mi = 0; mi < 4; ++mi)
#pragma unroll
        for (int ni = 0; ni < 4; ++ni) {
          acc[mi][ni] = __builtin_amdgcn_mfma_f32_16x16x32_bf16(af[mi][0], bfr[ni][0], acc[mi][ni], 0, 0, 0);
          acc[mi][ni] = __builtin_amdgcn_mfma_f32_16x16x32_bf16(af[mi][1], bfr[ni][1], acc[mi][ni], 0, 0, 0);
        }
      __syncthreads();  // all reads done before next stage overwrites
    }
  }

  if constexpr (MODE == 1) {
#pragma unroll
    for (int ni = 0; ni < 4; ++ni) {
      const int cog = co0 + wn * 64 + ni * 16 + (lane & 15);
      const float iv = bnp[1024 + cog];
      const float bb = bnp[1536 + cog];
#pragma unroll
      for (int mi = 0; mi < 4; ++mi)
#pragma unroll
        for (int r = 0; r < 4; ++r) {
          const int ml = wm * 64 + mi * 16 + (lane >> 4) * 4 + r;
          const int y = y0 + (ml >> 5), xx = ml & 31;
          float v = fmaxf(fmaf(acc[mi][ni][r], iv, bb), 0.f);
          Hout[((size_t)((n * 34 + y + 1) * 34 + (xx + 1))) * 512 + cog] = f2bf(v);
        }
    }
  } else {
#pragma unroll 1
    for (int hn = 0; hn < 2; ++hn) {
      if (wn == hn) {
#pragma unroll
        for (int ni = 0; ni < 4; ++ni)
#pragma unroll
          for (int mi = 0; mi < 4; ++mi)
#pragma unroll
            for (int r = 0; r < 4; ++r)
              smem[(ni * 16 + (lane & 15)) * 132 + wm * 64 + mi * 16 + (lane >> 4) * 4 + r] = acc[mi][ni][r];
      }
      __syncthreads();
      const int chunk = t & 31, cc0 = t >> 5;
#pragma unroll
      for (int cci = 0; cci < 8; ++cci) {
        const int cc = cci * 8 + cc0;
        const int m0 = chunk * 4;
        f32x4v v = *(const f32x4v*)&smem[cc * 132 + m0];
        const int cog = co0 + hn * 64 + cc;
        const size_t o = ((size_t)(n * 512 + cog)) * 1024 + y0 * 32 + m0;
        const f32x4v xr = *(const f32x4v*)(xres + o);
        v = v + xr;
        *(f32x4v*)(outp + o) = v;
      }
      __syncthreads();
    }
  }
}

// ---------------- launcher ----------------
extern "C" void kernel_launch(void* const* d_in, const int* in_sizes, int n_in,
                              void* d_out, int out_size, void* d_ws, size_t ws_size,
                              hipStream_t stream) {
  (void)in_sizes; (void)n_in; (void)out_size; (void)ws_size;
  const float* x    = (const float*)d_in[0];
  const float* bn1g = (const float*)d_in[1];
  const float* bn1b = (const float*)d_in[2];
  const float* bn1m = (const float*)d_in[3];
  const float* bn1v = (const float*)d_in[4];
  const float* w1   = (const float*)d_in[5];
  const float* bn2g = (const float*)d_in[6];
  const float* bn2b = (const float*)d_in[7];
  const float* bn2m = (const float*)d_in[8];
  const float* bn2v = (const float*)d_in[9];
  const float* w2   = (const float*)d_in[10];
  const float* fc1w = (const float*)d_in[11];
  const float* fc1b = (const float*)d_in[12];
  const float* fc2w = (const float*)d_in[13];
  const float* fc2b = (const float*)d_in[14];

  float* out = (float*)d_out;
  float* probeo = out + (size_t)64 * 512 * 32 * 32;

  char* ws = (char*)d_ws;
  unsigned short* Ap  = (unsigned short*)(ws);                 // 75,759,616 B padded NHWC bf16
  unsigned short* Hp  = (unsigned short*)(ws + 75759616);      // 75,759,616 B
  unsigned short* W1t = (unsigned short*)(ws + 151519232);     // 4,718,592 B
  unsigned short* W2t = (unsigned short*)(ws + 156237824);     // 4,718,592 B
  float* partial      = (float*)(ws + 160956416);              // 1,048,576 B
  float* maskp        = (float*)(ws + 162004992);              // 131,072 B
  float* bnp          = (float*)(ws + 162136064);              // 8,192 B

  hipMemsetAsync(Ap, 0, 75759616, stream);   // zero pad rings
  hipMemsetAsync(Hp, 0, 75759616, stream);
  bnprep<<<1, 512, 0, stream>>>(bn1g, bn1b, bn1m, bn1v, bn2g, bn2b, bn2m, bn2v, bnp);
  wtrans<<<18432, 256, 0, stream>>>(w1, w2, W1t, W2t);
  bn1_relu_stage<<<4096, 256, 0, stream>>>(x, bnp, Ap, partial);
  probe_mask<<<64, 256, 0, stream>>>(partial, fc1w, fc1b, fc2w, fc2b, maskp, probeo);
  apply_mask<<<dim3(289, 64), 256, 0, stream>>>(Ap, maskp);
  conv_gemm<1><<<2048, 256, 0, stream>>>(Ap, W1t, bnp, Hp, nullptr, nullptr);
  conv_gemm<2><<<2048, 256, 0, stream>>>(Hp, W2t, bnp, nullptr, x, out);
}

// Round 2
// 684.573 us; speedup vs baseline: 1.2913x; 1.2913x over previous
//
#include <hip/hip_runtime.h>
#include <stdint.h>

typedef __bf16 bf16x8 __attribute__((ext_vector_type(8)));
typedef float f32x4v __attribute__((ext_vector_type(4)));

typedef __attribute__((address_space(1))) const void gconst_t;
typedef __attribute__((address_space(3))) void lds_t;

// global -> LDS direct copy, 16 B per lane. LDS dest = wave-uniform base + lane*16.
#define GLL16(gp, sp) __builtin_amdgcn_global_load_lds((gconst_t*)(uintptr_t)(gp), (lds_t*)(uintptr_t)(sp), 16, 0, 0)

__device__ __forceinline__ unsigned short f2bf(float f) {
  unsigned int u = __float_as_uint(f);
  u = (u + 0x7FFFu + ((u >> 16) & 1u)) >> 16;
  return (unsigned short)u;
}
__device__ __forceinline__ float bf2f(unsigned int b) {
  return __uint_as_float(b << 16);
}

// ---------------- sizes ----------------
// x: (64,512,32,32) f32. padded NHWC: [n][34][34][512] bf16
#define SPP 1156  // 34*34

// ---------------- bn param prep ----------------
__global__ __launch_bounds__(512) void bnprep(
    const float* __restrict__ g1, const float* __restrict__ b1,
    const float* __restrict__ m1, const float* __restrict__ v1,
    const float* __restrict__ g2, const float* __restrict__ b2,
    const float* __restrict__ m2, const float* __restrict__ v2,
    float* __restrict__ bnp) {
  int t = threadIdx.x;
  float i1 = g1[t] * rsqrtf(v1[t] + 1e-5f);
  bnp[t] = i1;
  bnp[512 + t] = b1[t] - m1[t] * i1;
  float i2 = g2[t] * rsqrtf(v2[t] + 1e-5f);
  bnp[1024 + t] = i2;
  bnp[1536 + t] = b2[t] - m2[t] * i2;
}

// ---------------- weight transform: w[co][ci][dy][dx] f32 -> wt[tap][co][ci] bf16 ----------------
__global__ __launch_bounds__(256) void wtrans(const float* __restrict__ w1, const float* __restrict__ w2,
                                              unsigned short* __restrict__ w1t, unsigned short* __restrict__ w2t) {
  unsigned e = blockIdx.x * 256u + threadIdx.x;
  if (e >= 4718592u) return;
  const float* w = (e < 2359296u) ? w1 : w2;
  unsigned short* o = (e < 2359296u) ? w1t : w2t;
  unsigned r = (e < 2359296u) ? e : (e - 2359296u);
  unsigned ci = r & 511u, co = (r >> 9) & 511u, tt = r >> 18;
  o[r] = f2bf(w[(co * 512u + ci) * 9u + tt]);
}

// ---------------- bn1+relu, write padded NHWC bf16, per-(n,ci,yblk) partial sums ----------------
__global__ __launch_bounds__(256) void bn1_relu_stage(const float* __restrict__ x, const float* __restrict__ bnp,
                                                      unsigned short* __restrict__ Ap, float* __restrict__ partial) {
  int bid = blockIdx.x;
  int n = bid >> 6, ciblk = (bid >> 3) & 7, yblk = bid & 7;
  int ci0 = ciblk * 64, y0 = yblk * 4;
  int t = threadIdx.x;
  __shared__ __align__(16) float vals[64 * 128];
  __shared__ float ivs[64], bbs[64];
  if (t < 64) { ivs[t] = bnp[ci0 + t]; bbs[t] = bnp[512 + ci0 + t]; }
  __syncthreads();
#pragma unroll
  for (int i = 0; i < 8; ++i) {
    int f4 = i * 256 + t;
    int cil = f4 >> 5, xq = f4 & 31;
    const float* src = x + ((size_t)(n * 512 + ci0 + cil)) * 1024 + y0 * 32 + xq * 4;
    f32x4v v = *(const f32x4v*)src;
    float iv = ivs[cil], bb = bbs[cil];
    f32x4v r;
    r[0] = fmaxf(fmaf(v[0], iv, bb), 0.f);
    r[1] = fmaxf(fmaf(v[1], iv, bb), 0.f);
    r[2] = fmaxf(fmaf(v[2], iv, bb), 0.f);
    r[3] = fmaxf(fmaf(v[3], iv, bb), 0.f);
    *(f32x4v*)&vals[cil * 128 + xq * 4] = r;
  }
  __syncthreads();
  // partial sums per ci (deterministic)
  {
    int cil = t >> 2, q = t & 3;
    float s = 0.f;
#pragma unroll
    for (int j = 0; j < 32; ++j) s += vals[cil * 128 + q * 32 + j];
    s += __shfl_xor(s, 1);
    s += __shfl_xor(s, 2);
    if (q == 0) partial[((size_t)n * 512 + ci0 + cil) * 8 + yblk] = s;
  }
  // transpose to padded NHWC bf16
  {
    int yx = t >> 1, half = t & 1;
    int y = y0 + (yx >> 5), xx = yx & 31;
    unsigned short* dp = Ap + ((size_t)((n * 34 + y + 1) * 34 + (xx + 1))) * 512 + ci0 + half * 32;
    unsigned wrd[16];
#pragma unroll
    for (int j = 0; j < 16; ++j) {
      unsigned lo = f2bf(vals[(half * 32 + 2 * j) * 128 + yx]);
      unsigned hi = f2bf(vals[(half * 32 + 2 * j + 1) * 128 + yx]);
      wrd[j] = lo | (hi << 16);
    }
#pragma unroll
    for (int k = 0; k < 4; ++k) {
      uint4 u;
      u.x = wrd[k * 4]; u.y = wrd[k * 4 + 1]; u.z = wrd[k * 4 + 2]; u.w = wrd[k * 4 + 3];
      *(uint4*)(dp + k * 8) = u;
    }
  }
}

// ---------------- probe + analytic mask; writes pred_probe ----------------
__global__ __launch_bounds__(256) void probe_mask(const float* __restrict__ partial,
                                                  const float* __restrict__ fc1w, const float* __restrict__ fc1b,
                                                  const float* __restrict__ fc2w, const float* __restrict__ fc2b,
                                                  float* __restrict__ maskp, float* __restrict__ probeout) {
  int n = blockIdx.x, t = threadIdx.x;
  int lane = t & 63, wv = t >> 6;
  __shared__ float gl[512], sl[512], zl[240], hl[240], dzl[240], logl[10], red[4];
  __shared__ int idx2[2];
  for (int c = t; c < 512; c += 256) {
    const float* pp = partial + ((size_t)n * 512 + c) * 8;
    float s = 0.f;
#pragma unroll
    for (int j = 0; j < 8; ++j) s += pp[j];
    gl[c] = s * (1.f / 1024.f);
  }
  __syncthreads();
  if (t < 240) {
    float z = fc1b[t];
    const float* wr = fc1w + t * 512;
    for (int c = 0; c < 512; ++c) z = fmaf(gl[c], wr[c], z);
    zl[t] = z;
    float u = 5.f * z;
    float sp = (u > 20.f) ? u : log1pf(expf(u));
    hl[t] = sp * 0.2f;
  }
  __syncthreads();
  if (t < 10) {
    float L = fc2b[t];
    const float* wr = fc2w + t * 240;
    for (int h = 0; h < 240; ++h) L = fmaf(hl[h], wr[h], L);
    logl[t] = L;
    probeout[n * 10 + t] = L;
  }
  __syncthreads();
  if (t == 0) {
    float b1v = -1e30f, b2v = -1e30f; int i1 = 0, i2 = 0;
    for (int j = 0; j < 10; ++j) {
      float v = logl[j];
      if (v > b1v) { b2v = b1v; i2 = i1; b1v = v; i1 = j; }
      else if (v > b2v) { b2v = v; i2 = j; }
    }
    idx2[0] = i1; idx2[1] = i2;
  }
  __syncthreads();
  if (t < 240) {
    float dh = fc2w[idx2[0] * 240 + t] + fc2w[idx2[1] * 240 + t];
    float u = 5.f * zl[t];
    float sg = 1.f / (1.f + expf(-u));
    dzl[t] = dh * sg;
  }
  __syncthreads();
  for (int c = t; c < 512; c += 256) {
    float s = 0.f;
    for (int h = 0; h < 240; ++h) s = fmaf(dzl[h], fc1w[h * 512 + c], s);
    sl[c] = s;
  }
  __syncthreads();
  float m = fmaxf(sl[t], sl[t + 256]);
#pragma unroll
  for (int o = 32; o > 0; o >>= 1) m = fmaxf(m, __shfl_xor(m, o));
  if (lane == 0) red[wv] = m;
  __syncthreads();
  float mx = fmaxf(fmaxf(red[0], red[1]), fmaxf(red[2], red[3]));
  float e0 = expf(sl[t] - mx), e1 = expf(sl[t + 256] - mx);
  float sum = e0 + e1;
#pragma unroll
  for (int o = 32; o > 0; o >>= 1) sum += __shfl_xor(sum, o);
  __syncthreads();
  if (lane == 0) red[wv] = sum;
  __syncthreads();
  float inv = 2.f / (red[0] + red[1] + red[2] + red[3]);
  maskp[(size_t)n * 512 + t] = e0 * inv;
  maskp[(size_t)n * 512 + t + 256] = e1 * inv;
}

// ---------------- in-place mask multiply on padded NHWC bf16 ----------------
__global__ __launch_bounds__(256) void apply_mask(unsigned short* __restrict__ Ap, const float* __restrict__ maskp) {
  int n = blockIdx.y;
  size_t off = (size_t)n * (SPP * 512) + (size_t)blockIdx.x * 2048 + threadIdx.x * 8;
  int ci0 = (int)(threadIdx.x * 8) & 511;
  uint4 v = *(uint4*)(Ap + off);
  const float* mp = maskp + n * 512 + ci0;
  unsigned r0, r1;
  r0 = f2bf(bf2f(v.x & 0xFFFFu) * mp[0]); r1 = f2bf(bf2f(v.x >> 16) * mp[1]); v.x = r0 | (r1 << 16);
  r0 = f2bf(bf2f(v.y & 0xFFFFu) * mp[2]); r1 = f2bf(bf2f(v.y >> 16) * mp[3]); v.y = r0 | (r1 << 16);
  r0 = f2bf(bf2f(v.z & 0xFFFFu) * mp[4]); r1 = f2bf(bf2f(v.z >> 16) * mp[5]); v.z = r0 | (r1 << 16);
  r0 = f2bf(bf2f(v.w & 0xFFFFu) * mp[6]); r1 = f2bf(bf2f(v.w >> 16) * mp[7]); v.w = r0 | (r1 << 16);
  *(uint4*)(Ap + off) = v;
}

// ================= 256x256-tile 8-phase implicit-GEMM conv (m201 template) =================
// Tile: BM=256 pixels, BN=256 co, BK=64. 8 waves (2M x 4N), 512 thr, 128 KiB LDS.
// K-tiles: 9 taps x 8 = 72 (even). Iter = 2 K-tiles (buf0: phases 1-4, buf1: 5-8).
// LDS bytes: A = [buf][half][128][64]bf16 @ 0..65535; B same @ 65536..131071.
// st_16x32 swizzle: linear GLL dest + source chunk kq ^= (row>>1)&2; read k-term ^ ((lane&4)<<3).
// vmcnt ledger (loads, per wave; 2 per half-tile):
//   issue: ph1 u1A0, ph2 u1A1, ph3 u2B0, ph4 u2B1, ph5 u2A0, ph6 u2A1, ph7 u3B0, ph8 u3B1
//   W4 = vmcnt(4) covers u+1 (leaves u2B0,u2B1); W8 = vmcnt(4) covers u+2 (leaves u3B0,u3B1).
//   Region safety: every GLL issued >=1 barrier after its LDS region's last drained ds_read.
#define RD_A(QM, BOF) do {                                                    \
  const char* _p = ldsb + (BOF) + aRd + (QM) * 8192;                          \
  _Pragma("unroll") for (int mi = 0; mi < 4; ++mi) {                          \
    a[mi][0] = *(const bf16x8*)(_p + mi * 2048);                              \
    a[mi][1] = *(const bf16x8*)(_p + mi * 2048 + 64); }                       \
} while (0)

#define RD_B(QN, BOF) do {                                                    \
  const char* _p = ldsb + (BOF) + bRd + (QN) * 4096;                          \
  _Pragma("unroll") for (int ni = 0; ni < 2; ++ni) {                          \
    b[QN][ni][0] = *(const bf16x8*)(_p + ni * 2048);                          \
    b[QN][ni][1] = *(const bf16x8*)(_p + ni * 2048 + 64); }                   \
} while (0)

#define ST_A(BOF, H, AP) do {                                                 \
  GLL16((AP) + aOff[H][0], ldsb + (BOF) + (H) * 16384 + tb);                  \
  GLL16((AP) + aOff[H][1], ldsb + (BOF) + (H) * 16384 + 8192 + tb);           \
} while (0)

#define ST_B(BOF, H, BP) do {                                                 \
  GLL16((BP) + bOff[H][0], ldsb + 65536 + (BOF) + (H) * 16384 + tb);          \
  GLL16((BP) + bOff[H][1], ldsb + 65536 + (BOF) + (H) * 16384 + 8192 + tb);   \
} while (0)

#define MFMA_Q(QM, QN) do {                                                   \
  _Pragma("unroll") for (int mi = 0; mi < 4; ++mi)                            \
  _Pragma("unroll") for (int ni = 0; ni < 2; ++ni) {                          \
    acc[QM][QN][mi][ni] = __builtin_amdgcn_mfma_f32_16x16x32_bf16(            \
        a[mi][0], b[QN][ni][0], acc[QM][QN][mi][ni], 0, 0, 0);                \
    acc[QM][QN][mi][ni] = __builtin_amdgcn_mfma_f32_16x16x32_bf16(            \
        a[mi][1], b[QN][ni][1], acc[QM][QN][mi][ni], 0, 0, 0); }              \
} while (0)

#define BARR __builtin_amdgcn_s_barrier()
#define LGKM0 do { asm volatile("s_waitcnt lgkmcnt(0)" ::: "memory");         \
                   __builtin_amdgcn_sched_barrier(0); } while (0)
#define VM4 asm volatile("s_waitcnt vmcnt(4)" ::: "memory")
#define PRIO1 __builtin_amdgcn_s_setprio(1)
#define PRIO0 __builtin_amdgcn_s_setprio(0)

#define TILE_PTRS(KT, APn, BPn)                                               \
  const unsigned short *APn, *BPn;                                            \
  { int _kt = (KT); int _tap = _kt >> 3; int _kin = (_kt & 7) << 6;           \
    int _dy = (_tap * 11) >> 5; int _dx = _tap - _dy * 3;                     \
    APn = Ag + (size_t)(_dy * 34 + _dx) * 512 + _kin;                         \
    BPn = Wt + (size_t)_tap * 262144 + _kin; }

template <int MODE>
__global__ __launch_bounds__(512, 2) void conv256(
    const unsigned short* __restrict__ Ain,
    const unsigned short* __restrict__ Wt,
    const float* __restrict__ bnp,
    unsigned short* __restrict__ Hout,
    const float* __restrict__ xres,
    float* __restrict__ outp) {
  __shared__ __align__(16) char ldsb[131072];

  const int t = threadIdx.x;
  const int lane = t & 63;
  const int wv = t >> 6;
  const int wm = wv >> 2;  // 0..1: M-half -> A LDS half
  const int wn = wv & 3;   // 0..3: N quarter; B LDS half = wn>>1

  const int bid = blockIdx.x;
  const int swz = (bid & 7) * 64 + (bid >> 3);  // bijective: 512 % 8 == 0
  const int nt = swz & 1, mt = swz >> 1;
  const int n = mt >> 2, yblk = mt & 3;
  const int co0 = nt * 256;

  const unsigned short* Ag = Ain + (size_t)n * (SPP * 512);

  // staging offsets: chunk c = i*512+t; row lr = c>>3; source-swizzled kq.
  int aOff[2][2], bOff[2][2];
#pragma unroll
  for (int i = 0; i < 2; ++i) {
    const int c = i * 512 + t;
    const int lr = c >> 3;
    const int kq = (c & 7) ^ ((lr >> 1) & 2);
#pragma unroll
    for (int h = 0; h < 2; ++h) {
      aOff[h][i] = ((yblk * 8 + h * 4 + (lr >> 5)) * 34 + (lr & 31)) * 512 + kq * 8;
      bOff[h][i] = (co0 + h * 128 + lr) * 512 + kq * 8;
    }
  }
  const int tb = t * 16;
  const int kterm = ((lane >> 4) << 4) ^ ((lane & 4) << 3);
  const int aRd = wm * 16384 + (lane & 15) * 128 + kterm;
  const int bRd = 65536 + (wn >> 1) * 16384 + (((wn & 1) << 6) + (lane & 15)) * 128 + kterm;

  bf16x8 a[4][2];
  bf16x8 b[2][2][2];
  f32x4v acc[2][2][4][2];
  const f32x4v zero = {0.f, 0.f, 0.f, 0.f};
#pragma unroll
  for (int qm = 0; qm < 2; ++qm)
#pragma unroll
    for (int qn = 0; qn < 2; ++qn)
#pragma unroll
      for (int mi = 0; mi < 4; ++mi)
#pragma unroll
        for (int ni = 0; ni < 2; ++ni) acc[qm][qn][mi][ni] = zero;

  // ---- prologue: tile 0 full (buf0) + tile 1 B-halves (buf1) = 12 loads ----
  {
    TILE_PTRS(0, ap0, bp0);
    TILE_PTRS(1, ap1p, bp1p);
    ST_B(0, 0, bp0); ST_B(0, 1, bp0);
    ST_A(0, 0, ap0); ST_A(0, 1, ap0);
    ST_B(32768, 0, bp1p); ST_B(32768, 1, bp1p);
    (void)ap1p;
    VM4;
    BARR;
  }

  // ---- main loop: 36 iterations x 2 K-tiles ----
  for (int it = 0; it < 36; ++it) {
    const int u = 2 * it;
    TILE_PTRS(u + 1, ap1, bp1);
    (void)bp1;
    int kt2 = u + 2; if (kt2 > 71) kt2 = 71;  // tail clamp keeps vmcnt ledger exact
    int kt3 = u + 3; if (kt3 > 71) kt3 = 71;
    TILE_PTRS(kt2, ap2, bp2);
    TILE_PTRS(kt3, ap3, bp3);
    (void)ap3;

    // ph1: compute u q(0,0) from buf0
    RD_A(0, 0); RD_B(0, 0);
    ST_A(32768, 0, ap1);
    BARR; LGKM0;
    PRIO1; MFMA_Q(0, 0); PRIO0;
    BARR;
    // ph2: q(0,1)
    RD_B(1, 0);
    ST_A(32768, 1, ap1);
    BARR; LGKM0;
    PRIO1; MFMA_Q(0, 1); PRIO0;
    BARR;
    // ph3: q(1,1)
    RD_A(1, 0);
    ST_B(0, 0, bp2);
    BARR; LGKM0;
    PRIO1; MFMA_Q(1, 1); PRIO0;
    BARR;
    // ph4: q(1,0)  [no new ds_reads]
    ST_B(0, 1, bp2);
    BARR;
    PRIO1; MFMA_Q(1, 0); PRIO0;
    VM4;  // u+1 complete
    BARR;
    // ph5: compute u+1 q(0,0) from buf1
    RD_A(0, 32768); RD_B(0, 32768);
    ST_A(0, 0, ap2);
    BARR; LGKM0;
    PRIO1; MFMA_Q(0, 0); PRIO0;
    BARR;
    // ph6: q(0,1)
    RD_B(1, 32768);
    ST_A(0, 1, ap2);
    BARR; LGKM0;
    PRIO1; MFMA_Q(0, 1); PRIO0;
    BARR;
    // ph7: q(1,1)
    RD_A(1, 32768);
    ST_B(32768, 0, bp3);
    BARR; LGKM0;
    PRIO1; MFMA_Q(1, 1); PRIO0;
    BARR;
    // ph8: q(1,0)
    ST_B(32768, 1, bp3);
    BARR;
    PRIO1; MFMA_Q(1, 0); PRIO0;
    VM4;  // u+2 complete
    BARR;
  }
  asm volatile("s_waitcnt vmcnt(0)" ::: "memory");  // drain clamped tail loads before LDS reuse
  __syncthreads();

  if constexpr (MODE == 1) {
    // bn2 + relu -> padded NHWC bf16
#pragma unroll
    for (int qn = 0; qn < 2; ++qn)
#pragma unroll
      for (int ni = 0; ni < 2; ++ni) {
        const int cog = co0 + wn * 64 + qn * 32 + ni * 16 + (lane & 15);
        const float iv = bnp[1024 + cog];
        const float bb = bnp[1536 + cog];
#pragma unroll
        for (int qm = 0; qm < 2; ++qm)
#pragma unroll
          for (int mi = 0; mi < 4; ++mi)
#pragma unroll
            for (int r = 0; r < 4; ++r) {
              const int row = wm * 128 + qm * 64 + mi * 16 + (lane >> 4) * 4 + r;
              const int y = yblk * 8 + (row >> 5), xx = row & 31;
              const float v = fmaxf(fmaf(acc[qm][qn][mi][ni][r], iv, bb), 0.f);
              Hout[((size_t)((n * 34 + y + 1) * 34 + (xx + 1))) * 512 + cog] = f2bf(v);
            }
      }
  } else {
    // LDS transpose -> coalesced f32x4 NCHW + residual
    float* sm = (float*)ldsb;
    const int spat0 = yblk * 256;
#pragma unroll 1
    for (int h = 0; h < 4; ++h) {
      if (wn == h) {
#pragma unroll
        for (int qn = 0; qn < 2; ++qn)
#pragma unroll
          for (int ni = 0; ni < 2; ++ni)
#pragma unroll
            for (int qm = 0; qm < 2; ++qm)
#pragma unroll
              for (int mi = 0; mi < 4; ++mi)
#pragma unroll
                for (int r = 0; r < 4; ++r)
                  sm[(qn * 32 + ni * 16 + (lane & 15)) * 264 +
                     wm * 128 + qm * 64 + mi * 16 + (lane >> 4) * 4 + r] = acc[qm][qn][mi][ni][r];
      }
      __syncthreads();
#pragma unroll
      for (int j = 0; j < 8; ++j) {
        const int c = j * 512 + t;
        const int cc = c >> 6, px = (c & 63) * 4;
        f32x4v v = *(const f32x4v*)&sm[cc * 264 + px];
        const int cog = co0 + h * 64 + cc;
        const size_t o = ((size_t)(n * 512 + cog)) * 1024 + spat0 + px;
        const f32x4v xr = *(const f32x4v*)(xres + o);
        v = v + xr;
        *(f32x4v*)(outp + o) = v;
      }
      __syncthreads();
    }
  }
}

// ---------------- launcher ----------------
extern "C" void kernel_launch(void* const* d_in, const int* in_sizes, int n_in,
                              void* d_out, int out_size, void* d_ws, size_t ws_size,
                              hipStream_t stream) {
  (void)in_sizes; (void)n_in; (void)out_size; (void)ws_size;
  const float* x    = (const float*)d_in[0];
  const float* bn1g = (const float*)d_in[1];
  const float* bn1b = (const float*)d_in[2];
  const float* bn1m = (const float*)d_in[3];
  const float* bn1v = (const float*)d_in[4];
  const float* w1   = (const float*)d_in[5];
  const float* bn2g = (const float*)d_in[6];
  const float* bn2b = (const float*)d_in[7];
  const float* bn2m = (const float*)d_in[8];
  const float* bn2v = (const float*)d_in[9];
  const float* w2   = (const float*)d_in[10];
  const float* fc1w = (const float*)d_in[11];
  const float* fc1b = (const float*)d_in[12];
  const float* fc2w = (const float*)d_in[13];
  const float* fc2b = (const float*)d_in[14];

  float* out = (float*)d_out;
  float* probeo = out + (size_t)64 * 512 * 32 * 32;

  char* ws = (char*)d_ws;
  unsigned short* Ap  = (unsigned short*)(ws);                 // 75,759,616 B padded NHWC bf16
  unsigned short* Hp  = (unsigned short*)(ws + 75759616);      // 75,759,616 B
  unsigned short* W1t = (unsigned short*)(ws + 151519232);     // 4,718,592 B
  unsigned short* W2t = (unsigned short*)(ws + 156237824);     // 4,718,592 B
  float* partial      = (float*)(ws + 160956416);              // 1,048,576 B
  float* maskp        = (float*)(ws + 162004992);              // 131,072 B
  float* bnp          = (float*)(ws + 162136064);              // 8,192 B

  hipMemsetAsync(Ap, 0, 75759616, stream);  // zero pad rings
  hipMemsetAsync(Hp, 0, 75759616, stream);
  bnprep<<<1, 512, 0, stream>>>(bn1g, bn1b, bn1m, bn1v, bn2g, bn2b, bn2m, bn2v, bnp);
  wtrans<<<18432, 256, 0, stream>>>(w1, w2, W1t, W2t);
  bn1_relu_stage<<<4096, 256, 0, stream>>>(x, bnp, Ap, partial);
  probe_mask<<<64, 256, 0, stream>>>(partial, fc1w, fc1b, fc2w, fc2b, maskp, probeo);
  apply_mask<<<dim3(289, 64), 256, 0, stream>>>(Ap, maskp);
  conv256<1><<<512, 512, 0, stream>>>(Ap, W1t, bnp, Hp, nullptr, nullptr);
  conv256<2><<<512, 512, 0, stream>>>(Hp, W2t, bnp, nullptr, x, out);
}

// Round 3
// 616.346 us; speedup vs baseline: 1.4342x; 1.1107x over previous
//
#include <hip/hip_runtime.h>
#include <stdint.h>

typedef __bf16 bf16x8 __attribute__((ext_vector_type(8)));
typedef float f32x4v __attribute__((ext_vector_type(4)));

typedef __attribute__((address_space(1))) const void gconst_t;
typedef __attribute__((address_space(3))) void lds_t;

// global -> LDS direct copy, 16 B per lane. LDS dest = wave-uniform base + lane*16.
#define GLL16(gp, sp) __builtin_amdgcn_global_load_lds((gconst_t*)(uintptr_t)(gp), (lds_t*)(uintptr_t)(sp), 16, 0, 0)

__device__ __forceinline__ unsigned short f2bf(float f) {
  unsigned int u = __float_as_uint(f);
  u = (u + 0x7FFFu + ((u >> 16) & 1u)) >> 16;
  return (unsigned short)u;
}
__device__ __forceinline__ float bf2f(unsigned int b) {
  return __uint_as_float(b << 16);
}

// ---------------- sizes ----------------
// x: (64,512,32,32) f32. padded NHWC: [n][34][34][512] bf16
#define SPP 1156  // 34*34

// ---------------- bn param prep ----------------
__global__ __launch_bounds__(512) void bnprep(
    const float* __restrict__ g1, const float* __restrict__ b1,
    const float* __restrict__ m1, const float* __restrict__ v1,
    const float* __restrict__ g2, const float* __restrict__ b2,
    const float* __restrict__ m2, const float* __restrict__ v2,
    float* __restrict__ bnp) {
  int t = threadIdx.x;
  float i1 = g1[t] * rsqrtf(v1[t] + 1e-5f);
  bnp[t] = i1;
  bnp[512 + t] = b1[t] - m1[t] * i1;
  float i2 = g2[t] * rsqrtf(v2[t] + 1e-5f);
  bnp[1024 + t] = i2;
  bnp[1536 + t] = b2[t] - m2[t] * i2;
}

// ---------------- pad-ring zero for Ap and Hp (interiors are fully overwritten) ----------------
__global__ __launch_bounds__(256) void ring_zero(unsigned short* __restrict__ Ap,
                                                 unsigned short* __restrict__ Hp) {
  const int n = blockIdx.y;
  const int p = blockIdx.x * 4 + (threadIdx.x >> 6);  // 0..131 ring pixel
  const int lane = threadIdx.x & 63;
  int y, x;
  if (p < 34) { y = 0; x = p; }
  else if (p < 68) { y = 33; x = p - 34; }
  else if (p < 100) { y = p - 67; x = 0; }
  else { y = p - 99; x = 33; }
  const uint4 z = {0u, 0u, 0u, 0u};
  const size_t off = ((size_t)((n * 34 + y) * 34 + x)) * 512 + lane * 8;
  *(uint4*)(Ap + off) = z;
  *(uint4*)(Hp + off) = z;
}

// ---------------- weight transform: w[co][ci][dy][dx] f32 -> wt[tap][co][ci] bf16 ----------------
__global__ __launch_bounds__(256) void wtrans(const float* __restrict__ w1, const float* __restrict__ w2,
                                              unsigned short* __restrict__ w1t, unsigned short* __restrict__ w2t) {
  unsigned e = blockIdx.x * 256u + threadIdx.x;
  if (e >= 4718592u) return;
  const float* w = (e < 2359296u) ? w1 : w2;
  unsigned short* o = (e < 2359296u) ? w1t : w2t;
  unsigned r = (e < 2359296u) ? e : (e - 2359296u);
  unsigned ci = r & 511u, co = (r >> 9) & 511u, tt = r >> 18;
  o[r] = f2bf(w[(co * 512u + ci) * 9u + tt]);
}

// ---------------- bn1+relu, write padded NHWC bf16, per-(n,ci,yblk) partial sums ----------------
__global__ __launch_bounds__(256) void bn1_relu_stage(const float* __restrict__ x, const float* __restrict__ bnp,
                                                      unsigned short* __restrict__ Ap, float* __restrict__ partial) {
  int bid = blockIdx.x;
  int n = bid >> 6, ciblk = (bid >> 3) & 7, yblk = bid & 7;
  int ci0 = ciblk * 64, y0 = yblk * 4;
  int t = threadIdx.x;
  __shared__ __align__(16) float vals[64 * 128];
  __shared__ float ivs[64], bbs[64];
  if (t < 64) { ivs[t] = bnp[ci0 + t]; bbs[t] = bnp[512 + ci0 + t]; }
  __syncthreads();
#pragma unroll
  for (int i = 0; i < 8; ++i) {
    int f4 = i * 256 + t;
    int cil = f4 >> 5, xq = f4 & 31;
    const float* src = x + ((size_t)(n * 512 + ci0 + cil)) * 1024 + y0 * 32 + xq * 4;
    f32x4v v = *(const f32x4v*)src;
    float iv = ivs[cil], bb = bbs[cil];
    f32x4v r;
    r[0] = fmaxf(fmaf(v[0], iv, bb), 0.f);
    r[1] = fmaxf(fmaf(v[1], iv, bb), 0.f);
    r[2] = fmaxf(fmaf(v[2], iv, bb), 0.f);
    r[3] = fmaxf(fmaf(v[3], iv, bb), 0.f);
    *(f32x4v*)&vals[cil * 128 + xq * 4] = r;
  }
  __syncthreads();
  // partial sums per ci (deterministic)
  {
    int cil = t >> 2, q = t & 3;
    float s = 0.f;
#pragma unroll
    for (int j = 0; j < 32; ++j) s += vals[cil * 128 + q * 32 + j];
    s += __shfl_xor(s, 1);
    s += __shfl_xor(s, 2);
    if (q == 0) partial[((size_t)n * 512 + ci0 + cil) * 8 + yblk] = s;
  }
  // transpose to padded NHWC bf16
  {
    int yx = t >> 1, half = t & 1;
    int y = y0 + (yx >> 5), xx = yx & 31;
    unsigned short* dp = Ap + ((size_t)((n * 34 + y + 1) * 34 + (xx + 1))) * 512 + ci0 + half * 32;
    unsigned wrd[16];
#pragma unroll
    for (int j = 0; j < 16; ++j) {
      unsigned lo = f2bf(vals[(half * 32 + 2 * j) * 128 + yx]);
      unsigned hi = f2bf(vals[(half * 32 + 2 * j + 1) * 128 + yx]);
      wrd[j] = lo | (hi << 16);
    }
#pragma unroll
    for (int k = 0; k < 4; ++k) {
      uint4 u;
      u.x = wrd[k * 4]; u.y = wrd[k * 4 + 1]; u.z = wrd[k * 4 + 2]; u.w = wrd[k * 4 + 3];
      *(uint4*)(dp + k * 8) = u;
    }
  }
}

// ---------------- probe + analytic mask; writes pred_probe ----------------
__global__ __launch_bounds__(256) void probe_mask(const float* __restrict__ partial,
                                                  const float* __restrict__ fc1w, const float* __restrict__ fc1b,
                                                  const float* __restrict__ fc2w, const float* __restrict__ fc2b,
                                                  float* __restrict__ maskp, float* __restrict__ probeout) {
  int n = blockIdx.x, t = threadIdx.x;
  int lane = t & 63, wv = t >> 6;
  __shared__ float gl[512], sl[512], zl[240], hl[240], dzl[240], logl[10], red[4];
  __shared__ int idx2[2];
  for (int c = t; c < 512; c += 256) {
    const float* pp = partial + ((size_t)n * 512 + c) * 8;
    float s = 0.f;
#pragma unroll
    for (int j = 0; j < 8; ++j) s += pp[j];
    gl[c] = s * (1.f / 1024.f);
  }
  __syncthreads();
  if (t < 240) {
    float z = fc1b[t];
    const float* wr = fc1w + t * 512;
    for (int c = 0; c < 512; ++c) z = fmaf(gl[c], wr[c], z);
    zl[t] = z;
    float u = 5.f * z;
    float sp = (u > 20.f) ? u : log1pf(expf(u));
    hl[t] = sp * 0.2f;
  }
  __syncthreads();
  if (t < 10) {
    float L = fc2b[t];
    const float* wr = fc2w + t * 240;
    for (int h = 0; h < 240; ++h) L = fmaf(hl[h], wr[h], L);
    logl[t] = L;
    probeout[n * 10 + t] = L;
  }
  __syncthreads();
  if (t == 0) {
    float b1v = -1e30f, b2v = -1e30f; int i1 = 0, i2 = 0;
    for (int j = 0; j < 10; ++j) {
      float v = logl[j];
      if (v > b1v) { b2v = b1v; i2 = i1; b1v = v; i1 = j; }
      else if (v > b2v) { b2v = v; i2 = j; }
    }
    idx2[0] = i1; idx2[1] = i2;
  }
  __syncthreads();
  if (t < 240) {
    float dh = fc2w[idx2[0] * 240 + t] + fc2w[idx2[1] * 240 + t];
    float u = 5.f * zl[t];
    float sg = 1.f / (1.f + expf(-u));
    dzl[t] = dh * sg;
  }
  __syncthreads();
  for (int c = t; c < 512; c += 256) {
    float s = 0.f;
    for (int h = 0; h < 240; ++h) s = fmaf(dzl[h], fc1w[h * 512 + c], s);
    sl[c] = s;
  }
  __syncthreads();
  float m = fmaxf(sl[t], sl[t + 256]);
#pragma unroll
  for (int o = 32; o > 0; o >>= 1) m = fmaxf(m, __shfl_xor(m, o));
  if (lane == 0) red[wv] = m;
  __syncthreads();
  float mx = fmaxf(fmaxf(red[0], red[1]), fmaxf(red[2], red[3]));
  float e0 = expf(sl[t] - mx), e1 = expf(sl[t + 256] - mx);
  float sum = e0 + e1;
#pragma unroll
  for (int o = 32; o > 0; o >>= 1) sum += __shfl_xor(sum, o);
  __syncthreads();
  if (lane == 0) red[wv] = sum;
  __syncthreads();
  float inv = 2.f / (red[0] + red[1] + red[2] + red[3]);
  maskp[(size_t)n * 512 + t] = e0 * inv;
  maskp[(size_t)n * 512 + t + 256] = e1 * inv;
}

// ---------------- in-place mask multiply on padded NHWC bf16 ----------------
__global__ __launch_bounds__(256) void apply_mask(unsigned short* __restrict__ Ap, const float* __restrict__ maskp) {
  int n = blockIdx.y;
  size_t off = (size_t)n * (SPP * 512) + (size_t)blockIdx.x * 2048 + threadIdx.x * 8;
  int ci0 = (int)(threadIdx.x * 8) & 511;
  uint4 v = *(uint4*)(Ap + off);
  const float* mp = maskp + n * 512 + ci0;
  unsigned r0, r1;
  r0 = f2bf(bf2f(v.x & 0xFFFFu) * mp[0]); r1 = f2bf(bf2f(v.x >> 16) * mp[1]); v.x = r0 | (r1 << 16);
  r0 = f2bf(bf2f(v.y & 0xFFFFu) * mp[2]); r1 = f2bf(bf2f(v.y >> 16) * mp[3]); v.y = r0 | (r1 << 16);
  r0 = f2bf(bf2f(v.z & 0xFFFFu) * mp[4]); r1 = f2bf(bf2f(v.z >> 16) * mp[5]); v.z = r0 | (r1 << 16);
  r0 = f2bf(bf2f(v.w & 0xFFFFu) * mp[6]); r1 = f2bf(bf2f(v.w >> 16) * mp[7]); v.w = r0 | (r1 << 16);
  *(uint4*)(Ap + off) = v;
}

// ================= 256x256-tile 8-phase implicit-GEMM conv (m201 template) =================
// Tile: BM=256 pixels, BN=256 co, BK=64. 8 waves (2M x 4N), 512 thr, 128 KiB LDS.
// K-tiles: 9 taps x 8 = 72 (even). Iter = 2 K-tiles (buf0: phases 1-4, buf1: 5-8).
// LDS bytes: A = [buf][half][128][64]bf16 @ 0..65535; B same @ 65536..131071.
// FULL 3-bit XOR swizzle (G4 recipe): logical chunk q of row r stored at chunk q^(r&7).
//   write: linear GLL dest + inverse-permuted global source kq = (c&7) ^ (lr&7)
//   read:  k0 = ((lane>>4) ^ (lane&7))<<4, second fragment at addr^64 ((q+4)^s == (q^s)^4)
//   all fragment row strides (16/32/64 rows) are ==0 mod 8 -> one XOR term per lane.
// vmcnt ledger (loads, per wave; 2 per half-tile):
//   issue: ph1 u1A0, ph2 u1A1, ph3 u2B0, ph4 u2B1, ph5 u2A0, ph6 u2A1, ph7 u3B0, ph8 u3B1
//   W4 = vmcnt(4) covers u+1 (leaves u2B0,u2B1); W8 = vmcnt(4) covers u+2 (leaves u3B0,u3B1).
#define RD_A(QM, BOF) do {                                                    \
  const char* _p0 = ldsb + (BOF) + (QM) * 8192 + aRd0;                        \
  const char* _p1 = ldsb + (BOF) + (QM) * 8192 + aRd1;                        \
  _Pragma("unroll") for (int mi = 0; mi < 4; ++mi) {                          \
    a[mi][0] = *(const bf16x8*)(_p0 + mi * 2048);                             \
    a[mi][1] = *(const bf16x8*)(_p1 + mi * 2048); }                           \
} while (0)

#define RD_B(QN, BOF) do {                                                    \
  const char* _p0 = ldsb + (BOF) + (QN) * 4096 + bRd0;                        \
  const char* _p1 = ldsb + (BOF) + (QN) * 4096 + bRd1;                        \
  _Pragma("unroll") for (int ni = 0; ni < 2; ++ni) {                          \
    b[QN][ni][0] = *(const bf16x8*)(_p0 + ni * 2048);                         \
    b[QN][ni][1] = *(const bf16x8*)(_p1 + ni * 2048); }                       \
} while (0)

#define ST_A(BOF, H, AP) do {                                                 \
  GLL16((AP) + aOff[H][0], ldsb + (BOF) + (H) * 16384 + tb);                  \
  GLL16((AP) + aOff[H][1], ldsb + (BOF) + (H) * 16384 + 8192 + tb);           \
} while (0)

#define ST_B(BOF, H, BP) do {                                                 \
  GLL16((BP) + bOff[H][0], ldsb + 65536 + (BOF) + (H) * 16384 + tb);          \
  GLL16((BP) + bOff[H][1], ldsb + 65536 + (BOF) + (H) * 16384 + 8192 + tb);   \
} while (0)

#define MFMA_Q(QM, QN) do {                                                   \
  _Pragma("unroll") for (int mi = 0; mi < 4; ++mi)                            \
  _Pragma("unroll") for (int ni = 0; ni < 2; ++ni) {                          \
    acc[QM][QN][mi][ni] = __builtin_amdgcn_mfma_f32_16x16x32_bf16(            \
        a[mi][0], b[QN][ni][0], acc[QM][QN][mi][ni], 0, 0, 0);                \
    acc[QM][QN][mi][ni] = __builtin_amdgcn_mfma_f32_16x16x32_bf16(            \
        a[mi][1], b[QN][ni][1], acc[QM][QN][mi][ni], 0, 0, 0); }              \
} while (0)

#define BARR __builtin_amdgcn_s_barrier()
#define LGKM0 do { asm volatile("s_waitcnt lgkmcnt(0)" ::: "memory");         \
                   __builtin_amdgcn_sched_barrier(0); } while (0)
#define VM4 asm volatile("s_waitcnt vmcnt(4)" ::: "memory")
#define PRIO1 __builtin_amdgcn_s_setprio(1)
#define PRIO0 __builtin_amdgcn_s_setprio(0)

#define TILE_PTRS(KT, APn, BPn)                                               \
  const unsigned short *APn, *BPn;                                            \
  { int _kt = (KT); int _tap = _kt >> 3; int _kin = (_kt & 7) << 6;           \
    int _dy = (_tap * 11) >> 5; int _dx = _tap - _dy * 3;                     \
    APn = Ag + (size_t)(_dy * 34 + _dx) * 512 + _kin;                         \
    BPn = Wt + (size_t)_tap * 262144 + _kin; }

template <int MODE>
__global__ __launch_bounds__(512, 2) void conv256(
    const unsigned short* __restrict__ Ain,
    const unsigned short* __restrict__ Wt,
    const float* __restrict__ bnp,
    unsigned short* __restrict__ Hout,
    const float* __restrict__ xres,
    float* __restrict__ outp) {
  __shared__ __align__(16) char ldsb[131072];

  const int t = threadIdx.x;
  const int lane = t & 63;
  const int wv = t >> 6;
  const int wm = wv >> 2;  // 0..1: M-half -> A LDS half
  const int wn = wv & 3;   // 0..3: N quarter; B LDS half = wn>>1

  const int bid = blockIdx.x;
  const int swz = (bid & 7) * 64 + (bid >> 3);  // bijective: 512 % 8 == 0
  const int nt = swz & 1, mt = swz >> 1;
  const int n = mt >> 2, yblk = mt & 3;
  const int co0 = nt * 256;

  const unsigned short* Ag = Ain + (size_t)n * (SPP * 512);

  // staging offsets: chunk c = i*512+t; row lr = c>>3; source-swizzled kq = (c&7)^(lr&7).
  int aOff[2][2], bOff[2][2];
#pragma unroll
  for (int i = 0; i < 2; ++i) {
    const int c = i * 512 + t;
    const int lr = c >> 3;
    const int kq = (c & 7) ^ (lr & 7);
#pragma unroll
    for (int h = 0; h < 2; ++h) {
      aOff[h][i] = ((yblk * 8 + h * 4 + (lr >> 5)) * 34 + (lr & 31)) * 512 + kq * 8;
      bOff[h][i] = (co0 + h * 128 + lr) * 512 + kq * 8;
    }
  }
  const int tb = t * 16;
  const int k0 = (((lane >> 4) ^ (lane & 7)) << 4);
  const int aRd0 = wm * 16384 + (lane & 15) * 128 + k0;
  const int aRd1 = aRd0 ^ 64;
  const int bRd0 = 65536 + (wn >> 1) * 16384 + (((wn & 1) << 6) + (lane & 15)) * 128 + k0;
  const int bRd1 = bRd0 ^ 64;

  bf16x8 a[4][2];
  bf16x8 b[2][2][2];
  f32x4v acc[2][2][4][2];
  const f32x4v zero = {0.f, 0.f, 0.f, 0.f};
#pragma unroll
  for (int qm = 0; qm < 2; ++qm)
#pragma unroll
    for (int qn = 0; qn < 2; ++qn)
#pragma unroll
      for (int mi = 0; mi < 4; ++mi)
#pragma unroll
        for (int ni = 0; ni < 2; ++ni) acc[qm][qn][mi][ni] = zero;

  // ---- prologue: tile 0 full (buf0) + tile 1 B-halves (buf1) = 12 loads ----
  {
    TILE_PTRS(0, ap0, bp0);
    TILE_PTRS(1, ap1p, bp1p);
    ST_B(0, 0, bp0); ST_B(0, 1, bp0);
    ST_A(0, 0, ap0); ST_A(0, 1, ap0);
    ST_B(32768, 0, bp1p); ST_B(32768, 1, bp1p);
    (void)ap1p;
    VM4;
    BARR;
  }

  // ---- main loop: 36 iterations x 2 K-tiles ----
  for (int it = 0; it < 36; ++it) {
    const int u = 2 * it;
    TILE_PTRS(u + 1, ap1, bp1);
    (void)bp1;
    int kt2 = u + 2; if (kt2 > 71) kt2 = 71;  // tail clamp keeps vmcnt ledger exact
    int kt3 = u + 3; if (kt3 > 71) kt3 = 71;
    TILE_PTRS(kt2, ap2, bp2);
    TILE_PTRS(kt3, ap3, bp3);
    (void)ap3;

    // ph1: compute u q(0,0) from buf0
    RD_A(0, 0); RD_B(0, 0);
    ST_A(32768, 0, ap1);
    BARR; LGKM0;
    PRIO1; MFMA_Q(0, 0); PRIO0;
    BARR;
    // ph2: q(0,1)
    RD_B(1, 0);
    ST_A(32768, 1, ap1);
    BARR; LGKM0;
    PRIO1; MFMA_Q(0, 1); PRIO0;
    BARR;
    // ph3: q(1,1)
    RD_A(1, 0);
    ST_B(0, 0, bp2);
    BARR; LGKM0;
    PRIO1; MFMA_Q(1, 1); PRIO0;
    BARR;
    // ph4: q(1,0)  [no new ds_reads]
    ST_B(0, 1, bp2);
    BARR;
    PRIO1; MFMA_Q(1, 0); PRIO0;
    VM4;  // u+1 complete
    BARR;
    // ph5: compute u+1 q(0,0) from buf1
    RD_A(0, 32768); RD_B(0, 32768);
    ST_A(0, 0, ap2);
    BARR; LGKM0;
    PRIO1; MFMA_Q(0, 0); PRIO0;
    BARR;
    // ph6: q(0,1)
    RD_B(1, 32768);
    ST_A(0, 1, ap2);
    BARR; LGKM0;
    PRIO1; MFMA_Q(0, 1); PRIO0;
    BARR;
    // ph7: q(1,1)
    RD_A(1, 32768);
    ST_B(32768, 0, bp3);
    BARR; LGKM0;
    PRIO1; MFMA_Q(1, 1); PRIO0;
    BARR;
    // ph8: q(1,0)
    ST_B(32768, 1, bp3);
    BARR;
    PRIO1; MFMA_Q(1, 0); PRIO0;
    VM4;  // u+2 complete
    BARR;
  }
  asm volatile("s_waitcnt vmcnt(0)" ::: "memory");  // drain clamped tail loads before LDS reuse
  __syncthreads();

  if constexpr (MODE == 1) {
    // bn2 + relu -> padded NHWC bf16
#pragma unroll
    for (int qn = 0; qn < 2; ++qn)
#pragma unroll
      for (int ni = 0; ni < 2; ++ni) {
        const int cog = co0 + wn * 64 + qn * 32 + ni * 16 + (lane & 15);
        const float iv = bnp[1024 + cog];
        const float bb = bnp[1536 + cog];
#pragma unroll
        for (int qm = 0; qm < 2; ++qm)
#pragma unroll
          for (int mi = 0; mi < 4; ++mi)
#pragma unroll
            for (int r = 0; r < 4; ++r) {
              const int row = wm * 128 + qm * 64 + mi * 16 + (lane >> 4) * 4 + r;
              const int y = yblk * 8 + (row >> 5), xx = row & 31;
              const float v = fmaxf(fmaf(acc[qm][qn][mi][ni][r], iv, bb), 0.f);
              Hout[((size_t)((n * 34 + y + 1) * 34 + (xx + 1))) * 512 + cog] = f2bf(v);
            }
      }
  } else {
    // LDS transpose -> coalesced f32x4 NCHW + residual
    float* sm = (float*)ldsb;
    const int spat0 = yblk * 256;
#pragma unroll 1
    for (int h = 0; h < 4; ++h) {
      if (wn == h) {
#pragma unroll
        for (int qn = 0; qn < 2; ++qn)
#pragma unroll
          for (int ni = 0; ni < 2; ++ni)
#pragma unroll
            for (int qm = 0; qm < 2; ++qm)
#pragma unroll
              for (int mi = 0; mi < 4; ++mi)
#pragma unroll
                for (int r = 0; r < 4; ++r)
                  sm[(qn * 32 + ni * 16 + (lane & 15)) * 264 +
                     wm * 128 + qm * 64 + mi * 16 + (lane >> 4) * 4 + r] = acc[qm][qn][mi][ni][r];
      }
      __syncthreads();
#pragma unroll
      for (int j = 0; j < 8; ++j) {
        const int c = j * 512 + t;
        const int cc = c >> 6, px = (c & 63) * 4;
        f32x4v v = *(const f32x4v*)&sm[cc * 264 + px];
        const int cog = co0 + h * 64 + cc;
        const size_t o = ((size_t)(n * 512 + cog)) * 1024 + spat0 + px;
        const f32x4v xr = *(const f32x4v*)(xres + o);
        v = v + xr;
        *(f32x4v*)(outp + o) = v;
      }
      __syncthreads();
    }
  }
}

// ---------------- launcher ----------------
extern "C" void kernel_launch(void* const* d_in, const int* in_sizes, int n_in,
                              void* d_out, int out_size, void* d_ws, size_t ws_size,
                              hipStream_t stream) {
  (void)in_sizes; (void)n_in; (void)out_size; (void)ws_size;
  const float* x    = (const float*)d_in[0];
  const float* bn1g = (const float*)d_in[1];
  const float* bn1b = (const float*)d_in[2];
  const float* bn1m = (const float*)d_in[3];
  const float* bn1v = (const float*)d_in[4];
  const float* w1   = (const float*)d_in[5];
  const float* bn2g = (const float*)d_in[6];
  const float* bn2b = (const float*)d_in[7];
  const float* bn2m = (const float*)d_in[8];
  const float* bn2v = (const float*)d_in[9];
  const float* w2   = (const float*)d_in[10];
  const float* fc1w = (const float*)d_in[11];
  const float* fc1b = (const float*)d_in[12];
  const float* fc2w = (const float*)d_in[13];
  const float* fc2b = (const float*)d_in[14];

  float* out = (float*)d_out;
  float* probeo = out + (size_t)64 * 512 * 32 * 32;

  char* ws = (char*)d_ws;
  unsigned short* Ap  = (unsigned short*)(ws);                 // 75,759,616 B padded NHWC bf16
  unsigned short* Hp  = (unsigned short*)(ws + 75759616);      // 75,759,616 B
  unsigned short* W1t = (unsigned short*)(ws + 151519232);     // 4,718,592 B
  unsigned short* W2t = (unsigned short*)(ws + 156237824);     // 4,718,592 B
  float* partial      = (float*)(ws + 160956416);              // 1,048,576 B
  float* maskp        = (float*)(ws + 162004992);              // 131,072 B
  float* bnp          = (float*)(ws + 162136064);              // 8,192 B

  bnprep<<<1, 512, 0, stream>>>(bn1g, bn1b, bn1m, bn1v, bn2g, bn2b, bn2m, bn2v, bnp);
  ring_zero<<<dim3(33, 64), 256, 0, stream>>>(Ap, Hp);
  wtrans<<<18432, 256, 0, stream>>>(w1, w2, W1t, W2t);
  bn1_relu_stage<<<4096, 256, 0, stream>>>(x, bnp, Ap, partial);
  probe_mask<<<64, 256, 0, stream>>>(partial, fc1w, fc1b, fc2w, fc2b, maskp, probeo);
  apply_mask<<<dim3(289, 64), 256, 0, stream>>>(Ap, maskp);
  conv256<1><<<512, 512, 0, stream>>>(Ap, W1t, bnp, Hp, nullptr, nullptr);
  conv256<2><<<512, 512, 0, stream>>>(Hp, W2t, bnp, nullptr, x, out);
}

// Round 4
// 599.879 us; speedup vs baseline: 1.4736x; 1.0275x over previous
//
#include <hip/hip_runtime.h>
#include <stdint.h>

typedef __bf16 bf16x8 __attribute__((ext_vector_type(8)));
typedef float f32x4v __attribute__((ext_vector_type(4)));

typedef __attribute__((address_space(1))) const void gconst_t;
typedef __attribute__((address_space(3))) void lds_t;

// global -> LDS direct copy, 16 B per lane. LDS dest = wave-uniform base + lane*16.
#define GLL16(gp, sp) __builtin_amdgcn_global_load_lds((gconst_t*)(uintptr_t)(gp), (lds_t*)(uintptr_t)(sp), 16, 0, 0)

__device__ __forceinline__ unsigned short f2bf(float f) {
  unsigned int u = __float_as_uint(f);
  u = (u + 0x7FFFu + ((u >> 16) & 1u)) >> 16;
  return (unsigned short)u;
}
__device__ __forceinline__ float bf2f(unsigned int b) {
  return __uint_as_float(b << 16);
}

// ---------------- sizes ----------------
// x: (64,512,32,32) f32. padded NHWC: [n][34][34][512] bf16
#define SPP 1156  // 34*34

// ---------------- bn param prep ----------------
__global__ __launch_bounds__(512) void bnprep(
    const float* __restrict__ g1, const float* __restrict__ b1,
    const float* __restrict__ m1, const float* __restrict__ v1,
    const float* __restrict__ g2, const float* __restrict__ b2,
    const float* __restrict__ m2, const float* __restrict__ v2,
    float* __restrict__ bnp) {
  int t = threadIdx.x;
  float i1 = g1[t] * rsqrtf(v1[t] + 1e-5f);
  bnp[t] = i1;
  bnp[512 + t] = b1[t] - m1[t] * i1;
  float i2 = g2[t] * rsqrtf(v2[t] + 1e-5f);
  bnp[1024 + t] = i2;
  bnp[1536 + t] = b2[t] - m2[t] * i2;
}

// ---------------- pad-ring zero for Ap and Hp (interiors are fully overwritten) ----------------
__global__ __launch_bounds__(256) void ring_zero(unsigned short* __restrict__ Ap,
                                                 unsigned short* __restrict__ Hp) {
  const int n = blockIdx.y;
  const int p = blockIdx.x * 4 + (threadIdx.x >> 6);  // 0..131 ring pixel
  const int lane = threadIdx.x & 63;
  int y, x;
  if (p < 34) { y = 0; x = p; }
  else if (p < 68) { y = 33; x = p - 34; }
  else if (p < 100) { y = p - 67; x = 0; }
  else { y = p - 99; x = 33; }
  const uint4 z = {0u, 0u, 0u, 0u};
  const size_t off = ((size_t)((n * 34 + y) * 34 + x)) * 512 + lane * 8;
  *(uint4*)(Ap + off) = z;
  *(uint4*)(Hp + off) = z;
}

// ---------------- weight transform: w[co][ci][dy][dx] f32 -> wt[tap][co][ci] bf16 ----------------
__global__ __launch_bounds__(256) void wtrans(const float* __restrict__ w1, const float* __restrict__ w2,
                                              unsigned short* __restrict__ w1t, unsigned short* __restrict__ w2t) {
  unsigned e = blockIdx.x * 256u + threadIdx.x;
  if (e >= 4718592u) return;
  const float* w = (e < 2359296u) ? w1 : w2;
  unsigned short* o = (e < 2359296u) ? w1t : w2t;
  unsigned r = (e < 2359296u) ? e : (e - 2359296u);
  unsigned ci = r & 511u, co = (r >> 9) & 511u, tt = r >> 18;
  o[r] = f2bf(w[(co * 512u + ci) * 9u + tt]);
}

// ---------------- bn1+relu, write padded NHWC bf16, per-(n,ci,yblk) partial sums ----------------
__global__ __launch_bounds__(256) void bn1_relu_stage(const float* __restrict__ x, const float* __restrict__ bnp,
                                                      unsigned short* __restrict__ Ap, float* __restrict__ partial) {
  int bid = blockIdx.x;
  int n = bid >> 6, ciblk = (bid >> 3) & 7, yblk = bid & 7;
  int ci0 = ciblk * 64, y0 = yblk * 4;
  int t = threadIdx.x;
  __shared__ __align__(16) float vals[64 * 128];
  __shared__ float ivs[64], bbs[64];
  if (t < 64) { ivs[t] = bnp[ci0 + t]; bbs[t] = bnp[512 + ci0 + t]; }
  __syncthreads();
#pragma unroll
  for (int i = 0; i < 8; ++i) {
    int f4 = i * 256 + t;
    int cil = f4 >> 5, xq = f4 & 31;
    const float* src = x + ((size_t)(n * 512 + ci0 + cil)) * 1024 + y0 * 32 + xq * 4;
    f32x4v v = *(const f32x4v*)src;
    float iv = ivs[cil], bb = bbs[cil];
    f32x4v r;
    r[0] = fmaxf(fmaf(v[0], iv, bb), 0.f);
    r[1] = fmaxf(fmaf(v[1], iv, bb), 0.f);
    r[2] = fmaxf(fmaf(v[2], iv, bb), 0.f);
    r[3] = fmaxf(fmaf(v[3], iv, bb), 0.f);
    *(f32x4v*)&vals[cil * 128 + xq * 4] = r;
  }
  __syncthreads();
  // partial sums per ci (deterministic)
  {
    int cil = t >> 2, q = t & 3;
    float s = 0.f;
#pragma unroll
    for (int j = 0; j < 32; ++j) s += vals[cil * 128 + q * 32 + j];
    s += __shfl_xor(s, 1);
    s += __shfl_xor(s, 2);
    if (q == 0) partial[((size_t)n * 512 + ci0 + cil) * 8 + yblk] = s;
  }
  // transpose to padded NHWC bf16
  {
    int yx = t >> 1, half = t & 1;
    int y = y0 + (yx >> 5), xx = yx & 31;
    unsigned short* dp = Ap + ((size_t)((n * 34 + y + 1) * 34 + (xx + 1))) * 512 + ci0 + half * 32;
    unsigned wrd[16];
#pragma unroll
    for (int j = 0; j < 16; ++j) {
      unsigned lo = f2bf(vals[(half * 32 + 2 * j) * 128 + yx]);
      unsigned hi = f2bf(vals[(half * 32 + 2 * j + 1) * 128 + yx]);
      wrd[j] = lo | (hi << 16);
    }
#pragma unroll
    for (int k = 0; k < 4; ++k) {
      uint4 u;
      u.x = wrd[k * 4]; u.y = wrd[k * 4 + 1]; u.z = wrd[k * 4 + 2]; u.w = wrd[k * 4 + 3];
      *(uint4*)(dp + k * 8) = u;
    }
  }
}

// ---------------- probe + analytic mask; writes pred_probe ----------------
__global__ __launch_bounds__(256) void probe_mask(const float* __restrict__ partial,
                                                  const float* __restrict__ fc1w, const float* __restrict__ fc1b,
                                                  const float* __restrict__ fc2w, const float* __restrict__ fc2b,
                                                  float* __restrict__ maskp, float* __restrict__ probeout) {
  int n = blockIdx.x, t = threadIdx.x;
  int lane = t & 63, wv = t >> 6;
  __shared__ float gl[512], sl[512], zl[240], hl[240], dzl[240], logl[10], red[4];
  __shared__ int idx2[2];
  for (int c = t; c < 512; c += 256) {
    const float* pp = partial + ((size_t)n * 512 + c) * 8;
    float s = 0.f;
#pragma unroll
    for (int j = 0; j < 8; ++j) s += pp[j];
    gl[c] = s * (1.f / 1024.f);
  }
  __syncthreads();
  if (t < 240) {
    float z = fc1b[t];
    const float* wr = fc1w + t * 512;
    for (int c = 0; c < 512; ++c) z = fmaf(gl[c], wr[c], z);
    zl[t] = z;
    float u = 5.f * z;
    float sp = (u > 20.f) ? u : log1pf(expf(u));
    hl[t] = sp * 0.2f;
  }
  __syncthreads();
  if (t < 10) {
    float L = fc2b[t];
    const float* wr = fc2w + t * 240;
    for (int h = 0; h < 240; ++h) L = fmaf(hl[h], wr[h], L);
    logl[t] = L;
    probeout[n * 10 + t] = L;
  }
  __syncthreads();
  if (t == 0) {
    float b1v = -1e30f, b2v = -1e30f; int i1 = 0, i2 = 0;
    for (int j = 0; j < 10; ++j) {
      float v = logl[j];
      if (v > b1v) { b2v = b1v; i2 = i1; b1v = v; i1 = j; }
      else if (v > b2v) { b2v = v; i2 = j; }
    }
    idx2[0] = i1; idx2[1] = i2;
  }
  __syncthreads();
  if (t < 240) {
    float dh = fc2w[idx2[0] * 240 + t] + fc2w[idx2[1] * 240 + t];
    float u = 5.f * zl[t];
    float sg = 1.f / (1.f + expf(-u));
    dzl[t] = dh * sg;
  }
  __syncthreads();
  for (int c = t; c < 512; c += 256) {
    float s = 0.f;
    for (int h = 0; h < 240; ++h) s = fmaf(dzl[h], fc1w[h * 512 + c], s);
    sl[c] = s;
  }
  __syncthreads();
  float m = fmaxf(sl[t], sl[t + 256]);
#pragma unroll
  for (int o = 32; o > 0; o >>= 1) m = fmaxf(m, __shfl_xor(m, o));
  if (lane == 0) red[wv] = m;
  __syncthreads();
  float mx = fmaxf(fmaxf(red[0], red[1]), fmaxf(red[2], red[3]));
  float e0 = expf(sl[t] - mx), e1 = expf(sl[t + 256] - mx);
  float sum = e0 + e1;
#pragma unroll
  for (int o = 32; o > 0; o >>= 1) sum += __shfl_xor(sum, o);
  __syncthreads();
  if (lane == 0) red[wv] = sum;
  __syncthreads();
  float inv = 2.f / (red[0] + red[1] + red[2] + red[3]);
  maskp[(size_t)n * 512 + t] = e0 * inv;
  maskp[(size_t)n * 512 + t + 256] = e1 * inv;
}

// ---------------- in-place mask multiply on padded NHWC bf16 ----------------
__global__ __launch_bounds__(256) void apply_mask(unsigned short* __restrict__ Ap, const float* __restrict__ maskp) {
  int n = blockIdx.y;
  size_t off = (size_t)n * (SPP * 512) + (size_t)blockIdx.x * 2048 + threadIdx.x * 8;
  int ci0 = (int)(threadIdx.x * 8) & 511;
  uint4 v = *(uint4*)(Ap + off);
  const float* mp = maskp + n * 512 + ci0;
  unsigned r0, r1;
  r0 = f2bf(bf2f(v.x & 0xFFFFu) * mp[0]); r1 = f2bf(bf2f(v.x >> 16) * mp[1]); v.x = r0 | (r1 << 16);
  r0 = f2bf(bf2f(v.y & 0xFFFFu) * mp[2]); r1 = f2bf(bf2f(v.y >> 16) * mp[3]); v.y = r0 | (r1 << 16);
  r0 = f2bf(bf2f(v.z & 0xFFFFu) * mp[4]); r1 = f2bf(bf2f(v.z >> 16) * mp[5]); v.z = r0 | (r1 << 16);
  r0 = f2bf(bf2f(v.w & 0xFFFFu) * mp[6]); r1 = f2bf(bf2f(v.w >> 16) * mp[7]); v.w = r0 | (r1 << 16);
  *(uint4*)(Ap + off) = v;
}

// ================= 256x256 implicit-GEMM conv, tap-reuse A panel (v2) =================
// K order: k8 outer (8) x tap inner (9). A staged ONCE per k8 as a 384-slot panel
// [slot][64k] bf16 (slots = 10 rows x 34 px used; 44 garbage slots never read),
// single-buffered at LDS [0, 49152). All 9 taps read A at slot (my+dy)*34 + x+dx.
// B: 3-ring [49152 + buf*32768), half +16384, staged per tap-step with distance-2
// prefetch; Bbuf = tap%3 (9%3==0 makes this k8-invariant).
// Swizzle (both-sides, rule 21): store global chunk q^(s&7) at LDS chunk q of slot s
// (source-permuted, linear GLL dest); reads XOR back. A-read XOR via lterm[8]
// (compile-time indices only — taps fully macro-unrolled).
// Phases per tap-step: ph1 {RD_A(0),RD_B(0),ST_B h0} ph2 {RD_B(1),ST_B h1}
// ph3 {RD_A(1), 32 MFMA, VM4}. tap8 splits ph3 into ph3a/ph3b to host the 6 A-GLL
// (issued >=1 barrier after the panel's last drained read) and drains with VM0
// before the next k8's first read.
// vmcnt ledger (per wave): 4 B-GLL issued per step (ph1/ph2), VM4 at step end
// leaves exactly B(ts+2); B(ts+1) drained. tap8: +6 A-GLL then VM0.
#define RD_A(QM, TAP) do {                                                    \
  const int _c0 = ((((QM) * 2 + (TAP) / 3) * 34 + (TAP) % 3)) * 128;          \
  const int _l0 = lterm[((((QM) * 2 + (TAP) / 3) * 34 + (TAP) % 3)) & 7];     \
  const int _c1 = _c0 + 8704;                                                 \
  const int _l1 = lterm[((((QM) * 2 + (TAP) / 3) * 34 + (TAP) % 3) + 4) & 7]; \
  a[0][0] = *(const bf16x8*)(ldsAW + _c0 + _l0);                              \
  a[0][1] = *(const bf16x8*)(ldsAW + _c0 + (_l0 ^ 64));                       \
  a[1][0] = *(const bf16x8*)(ldsAW + _c0 + 2048 + _l0);                       \
  a[1][1] = *(const bf16x8*)(ldsAW + _c0 + 2048 + (_l0 ^ 64));                \
  a[2][0] = *(const bf16x8*)(ldsAW + _c1 + _l1);                              \
  a[2][1] = *(const bf16x8*)(ldsAW + _c1 + (_l1 ^ 64));                       \
  a[3][0] = *(const bf16x8*)(ldsAW + _c1 + 2048 + _l1);                       \
  a[3][1] = *(const bf16x8*)(ldsAW + _c1 + 2048 + (_l1 ^ 64));                \
} while (0)

#define RD_B(QN, BUFR) do {                                                   \
  const int _b0 = 49152 + (BUFR) * 32768 + (QN) * 4096 + bRdC;                \
  _Pragma("unroll") for (int ni = 0; ni < 2; ++ni) {                          \
    b[QN][ni][0] = *(const bf16x8*)(ldsb + _b0 + ni * 2048);                  \
    b[QN][ni][1] = *(const bf16x8*)(ldsb + (_b0 ^ 64) + ni * 2048); }         \
} while (0)

#define ST_B(BUFW, H, BP) do {                                                \
  GLL16((BP) + bOff[H][0], ldsb + 49152 + (BUFW) * 32768 + (H) * 16384 + tb); \
  GLL16((BP) + bOff[H][1],                                                    \
        ldsb + 49152 + (BUFW) * 32768 + (H) * 16384 + 8192 + tb);             \
} while (0)

#define ST_A3(AP) do {                                                        \
  GLL16((AP) + aSrc[0], ldsb + tb);                                           \
  GLL16((AP) + aSrc[1], ldsb + 8192 + tb);                                    \
  GLL16((AP) + aSrc[2], ldsb + 16384 + tb);                                   \
  GLL16((AP) + aSrc[3], ldsb + 24576 + tb);                                   \
  GLL16((AP) + aSrc[4], ldsb + 32768 + tb);                                   \
  GLL16((AP) + aSrc[5], ldsb + 40960 + tb);                                   \
} while (0)

#define MFMA_Q(QM, QN) do {                                                   \
  _Pragma("unroll") for (int mi = 0; mi < 4; ++mi)                            \
  _Pragma("unroll") for (int ni = 0; ni < 2; ++ni) {                          \
    acc[QM][QN][mi][ni] = __builtin_amdgcn_mfma_f32_16x16x32_bf16(            \
        a[mi][0], b[QN][ni][0], acc[QM][QN][mi][ni], 0, 0, 0);                \
    acc[QM][QN][mi][ni] = __builtin_amdgcn_mfma_f32_16x16x32_bf16(            \
        a[mi][1], b[QN][ni][1], acc[QM][QN][mi][ni], 0, 0, 0); }              \
} while (0)

#define BARR __builtin_amdgcn_s_barrier()
#define LGKM0 do { asm volatile("s_waitcnt lgkmcnt(0)" ::: "memory");         \
                   __builtin_amdgcn_sched_barrier(0); } while (0)
#define VM4 asm volatile("s_waitcnt vmcnt(4)" ::: "memory")
#define VM0 asm volatile("s_waitcnt vmcnt(0)" ::: "memory")
#define PRIO1 __builtin_amdgcn_s_setprio(1)
#define PRIO0 __builtin_amdgcn_s_setprio(0)

#define TAPSTEP(TAP) do {                                                     \
  const unsigned short* _bp2;                                                 \
  if ((TAP) <= 6)      _bp2 = Wt + (size_t)((TAP) + 2) * 262144 + k8 * 64;    \
  else if ((TAP) == 7) _bp2 = (k8 < 7) ? Wt + (size_t)(k8 + 1) * 64           \
                                       : Wt + (size_t)8 * 262144 + 7 * 64;    \
  else                 _bp2 = (k8 < 7) ? Wt + 262144 + (size_t)(k8 + 1) * 64  \
                                       : Wt + (size_t)8 * 262144 + 7 * 64;    \
  /* ph1 */                                                                   \
  RD_A(0, TAP); RD_B(0, (TAP) % 3);                                           \
  ST_B(((TAP) + 2) % 3, 0, _bp2);                                             \
  BARR; LGKM0;                                                                \
  PRIO1; MFMA_Q(0, 0); PRIO0;                                                 \
  BARR;                                                                       \
  /* ph2 */                                                                   \
  RD_B(1, (TAP) % 3);                                                         \
  ST_B(((TAP) + 2) % 3, 1, _bp2);                                             \
  BARR; LGKM0;                                                                \
  PRIO1; MFMA_Q(0, 1); PRIO0;                                                 \
  BARR;                                                                       \
  /* ph3 */                                                                   \
  RD_A(1, TAP);                                                               \
  BARR; LGKM0;                                                                \
  if ((TAP) < 8) {                                                            \
    PRIO1; MFMA_Q(1, 1); MFMA_Q(1, 0); PRIO0;                                 \
    VM4; BARR;                                                                \
  } else {                                                                    \
    PRIO1; MFMA_Q(1, 1); PRIO0;                                               \
    BARR;                                                                     \
    if (k8 < 7) { ST_A3(Ag + (size_t)(k8 + 1) * 64); }                        \
    BARR;                                                                     \
    PRIO1; MFMA_Q(1, 0); PRIO0;                                               \
    VM0; BARR;                                                                \
  }                                                                           \
} while (0)

template <int MODE>
__global__ __launch_bounds__(512, 2) void conv256(
    const unsigned short* __restrict__ Ain,
    const unsigned short* __restrict__ Wt,
    const float* __restrict__ bnp,
    unsigned short* __restrict__ Hout,
    const float* __restrict__ xres,
    float* __restrict__ outp) {
  __shared__ __align__(16) char ldsb[147456];  // A panel 48K + B 3-ring 96K

  const int t = threadIdx.x;
  const int lane = t & 63;
  const int wv = t >> 6;
  const int wm = wv >> 2;  // 0..1: M-half
  const int wn = wv & 3;   // 0..3: N quarter; B LDS half = wn>>1

  const int bid = blockIdx.x;
  const int swz = (bid & 7) * 64 + (bid >> 3);  // bijective: 512 % 8 == 0
  const int nt = swz & 1, mt = swz >> 1;
  const int n = mt >> 2, yblk = mt & 3;
  const int co0 = nt * 256;

  const unsigned short* Ag = Ain + (size_t)n * (SPP * 512);

  // B staging offsets: chunk c = i*512+t; row lr = c>>3; source-swizzled kq.
  int bOff[2][2];
#pragma unroll
  for (int i = 0; i < 2; ++i) {
    const int c = i * 512 + t;
    const int lr = c >> 3;
    const int kq = (c & 7) ^ (lr & 7);
#pragma unroll
    for (int h = 0; h < 2; ++h)
      bOff[h][i] = (co0 + h * 128 + lr) * 512 + kq * 8;
  }
  // A panel staging sources: round r covers slots [r*64, r*64+64)
  int aSrc[6];
#pragma unroll
  for (int r = 0; r < 6; ++r) {
    const int s = r * 64 + (t >> 3);
    const int kq = (t & 7) ^ (s & 7);
    aSrc[r] = (yblk * 272 + s) * 512 + kq * 8;
  }
  const int tb = t * 16;
  const int k0 = ((lane >> 4) ^ (lane & 7)) << 4;
  // per-lane A-read term for wave-uniform slot base == m (mod 8)
  int lterm[8];
#pragma unroll
  for (int m = 0; m < 8; ++m)
    lterm[m] = (lane & 15) * 128 + (((lane >> 4) ^ ((m + (lane & 15)) & 7)) << 4);
  const char* ldsAW = ldsb + wm * 17408;  // wm*136 slots * 128 B
  const int bRdC = (wn >> 1) * 16384 + (((wn & 1) << 6) + (lane & 15)) * 128 + k0;

  bf16x8 a[4][2];
  bf16x8 b[2][2][2];
  f32x4v acc[2][2][4][2];
  const f32x4v zero = {0.f, 0.f, 0.f, 0.f};
#pragma unroll
  for (int qm = 0; qm < 2; ++qm)
#pragma unroll
    for (int qn = 0; qn < 2; ++qn)
#pragma unroll
      for (int mi = 0; mi < 4; ++mi)
#pragma unroll
        for (int ni = 0; ni < 2; ++ni) acc[qm][qn][mi][ni] = zero;

  // ---- prologue: A panel (k8=0) + B(tap0) + B(tap1) ----
  {
    ST_A3(Ag);
    ST_B(0, 0, Wt); ST_B(0, 1, Wt);
    ST_B(1, 0, Wt + 262144); ST_B(1, 1, Wt + 262144);
    VM0; BARR;
  }

  // ---- main loop: 8 k8 x 9 taps ----
  for (int k8 = 0; k8 < 8; ++k8) {
    TAPSTEP(0); TAPSTEP(1); TAPSTEP(2);
    TAPSTEP(3); TAPSTEP(4); TAPSTEP(5);
    TAPSTEP(6); TAPSTEP(7); TAPSTEP(8);
  }
  VM0;
  __syncthreads();

  if constexpr (MODE == 1) {
    // bn2 + relu -> padded NHWC bf16
#pragma unroll
    for (int qn = 0; qn < 2; ++qn)
#pragma unroll
      for (int ni = 0; ni < 2; ++ni) {
        const int cog = co0 + wn * 64 + qn * 32 + ni * 16 + (lane & 15);
        const float iv = bnp[1024 + cog];
        const float bb = bnp[1536 + cog];
#pragma unroll
        for (int qm = 0; qm < 2; ++qm)
#pragma unroll
          for (int mi = 0; mi < 4; ++mi)
#pragma unroll
            for (int r = 0; r < 4; ++r) {
              const int row = wm * 128 + qm * 64 + mi * 16 + (lane >> 4) * 4 + r;
              const int y = yblk * 8 + (row >> 5), xx = row & 31;
              const float v = fmaxf(fmaf(acc[qm][qn][mi][ni][r], iv, bb), 0.f);
              Hout[((size_t)((n * 34 + y + 1) * 34 + (xx + 1))) * 512 + cog] = f2bf(v);
            }
      }
  } else {
    // LDS transpose -> coalesced f32x4 NCHW + residual (uses ldsb[0..67583])
    float* sm = (float*)ldsb;
    const int spat0 = yblk * 256;
#pragma unroll 1
    for (int h = 0; h < 4; ++h) {
      if (wn == h) {
#pragma unroll
        for (int qn = 0; qn < 2; ++qn)
#pragma unroll
          for (int ni = 0; ni < 2; ++ni)
#pragma unroll
            for (int qm = 0; qm < 2; ++qm)
#pragma unroll
              for (int mi = 0; mi < 4; ++mi)
#pragma unroll
                for (int r = 0; r < 4; ++r)
                  sm[(qn * 32 + ni * 16 + (lane & 15)) * 264 +
                     wm * 128 + qm * 64 + mi * 16 + (lane >> 4) * 4 + r] = acc[qm][qn][mi][ni][r];
      }
      __syncthreads();
#pragma unroll
      for (int j = 0; j < 8; ++j) {
        const int c = j * 512 + t;
        const int cc = c >> 6, px = (c & 63) * 4;
        f32x4v v = *(const f32x4v*)&sm[cc * 264 + px];
        const int cog = co0 + h * 64 + cc;
        const size_t o = ((size_t)(n * 512 + cog)) * 1024 + spat0 + px;
        const f32x4v xr = *(const f32x4v*)(xres + o);
        v = v + xr;
        *(f32x4v*)(outp + o) = v;
      }
      __syncthreads();
    }
  }
}

// ---------------- launcher ----------------
extern "C" void kernel_launch(void* const* d_in, const int* in_sizes, int n_in,
                              void* d_out, int out_size, void* d_ws, size_t ws_size,
                              hipStream_t stream) {
  (void)in_sizes; (void)n_in; (void)out_size; (void)ws_size;
  const float* x    = (const float*)d_in[0];
  const float* bn1g = (const float*)d_in[1];
  const float* bn1b = (const float*)d_in[2];
  const float* bn1m = (const float*)d_in[3];
  const float* bn1v = (const float*)d_in[4];
  const float* w1   = (const float*)d_in[5];
  const float* bn2g = (const float*)d_in[6];
  const float* bn2b = (const float*)d_in[7];
  const float* bn2m = (const float*)d_in[8];
  const float* bn2v = (const float*)d_in[9];
  const float* w2   = (const float*)d_in[10];
  const float* fc1w = (const float*)d_in[11];
  const float* fc1b = (const float*)d_in[12];
  const float* fc2w = (const float*)d_in[13];
  const float* fc2b = (const float*)d_in[14];

  float* out = (float*)d_out;
  float* probeo = out + (size_t)64 * 512 * 32 * 32;

  char* ws = (char*)d_ws;
  unsigned short* Ap  = (unsigned short*)(ws);                 // 75,759,616 B padded NHWC bf16
  unsigned short* Hp  = (unsigned short*)(ws + 75759616);      // 75,759,616 B
  unsigned short* W1t = (unsigned short*)(ws + 151519232);     // 4,718,592 B
  unsigned short* W2t = (unsigned short*)(ws + 156237824);     // 4,718,592 B
  float* partial      = (float*)(ws + 160956416);              // 1,048,576 B
  float* maskp        = (float*)(ws + 162004992);              // 131,072 B
  float* bnp          = (float*)(ws + 162136064);              // 8,192 B

  bnprep<<<1, 512, 0, stream>>>(bn1g, bn1b, bn1m, bn1v, bn2g, bn2b, bn2m, bn2v, bnp);
  ring_zero<<<dim3(33, 64), 256, 0, stream>>>(Ap, Hp);
  wtrans<<<18432, 256, 0, stream>>>(w1, w2, W1t, W2t);
  bn1_relu_stage<<<4096, 256, 0, stream>>>(x, bnp, Ap, partial);
  probe_mask<<<64, 256, 0, stream>>>(partial, fc1w, fc1b, fc2w, fc2b, maskp, probeo);
  apply_mask<<<dim3(289, 64), 256, 0, stream>>>(Ap, maskp);
  conv256<1><<<512, 512, 0, stream>>>(Ap, W1t, bnp, Hp, nullptr, nullptr);
  conv256<2><<<512, 512, 0, stream>>>(Hp, W2t, bnp, nullptr, x, out);
}